// Round 3
// baseline (453.763 us; speedup 1.0000x reference)
//
#include <hip/hip_runtime.h>
#include <float.h>
#include <math.h>

// VQ nearest-codebook: z_e (64,256,32,32) fp32 NCHW, codebook (512,256) fp32.
// token t = n*1024 + hw; feature d at z_e[n*262144 + d*1024 + hw].
// d_out: [0,65536) = q as float; [65536,...) = z_q fp32 NCHW.
//
// Correctness model: harness ref (np, fp32) computes
//   dists = x_sq - 2*(x@cb.T) + w_sq   (fp32; adding x_sq~256 quantizes to ~1.5e-5)
//   q = argmin (first occurrence = lowest k on quantized ties)
// We scan with fp32 m = x.w - 0.5|w|^2 (error ~1e-7 << quantum), keep top-4,
// then adjudicate with the ref-identical quantized fp32 distance:
//   dist = fl32( fl32(xsq_np - 2*fl32(xw_fp64)) + wsq_np )
// xsq_np / wsq_np replicate numpy pairwise fp32 summation bitwise.

#define KCODES 512
#define DDIM   256
#define HWSZ   1024
#define TTOK   65536
#define KG     8              // k-groups per block
#define CPG    (KCODES / KG)  // 64 codes per group
#define CC     8              // codes per chunk per group
#define NCHUNK (CPG / CC)     // 8
#define RTOK   4              // tokens per thread
#define TPB    128            // tokens per block
#define NBLK   (TTOK / TPB)   // 512

// ------------------------------------------------------------ wsq (np) -----
// Bitwise replication of np.sum(cb*cb, axis=1) float32 pairwise (n=256:
// two halves of 128, each with 8 accumulators over 16 sequential steps).
__global__ __launch_bounds__(256) void vq_wsq_np(const float* __restrict__ cb,
                                                 float* __restrict__ wsq) {
#pragma clang fp contract(off)
    const int k = blockIdx.x * 256 + threadIdx.x;
    if (k >= KCODES) return;
    const float* p = cb + (size_t)k * DDIM;
    float sh[2];
    #pragma unroll
    for (int h = 0; h < 2; ++h) {
        const float* q = p + h * 128;
        float r[8];
        #pragma unroll
        for (int j = 0; j < 8; ++j) { float v = q[j]; r[j] = v * v; }
        #pragma unroll
        for (int i = 8; i < 128; i += 8) {
            #pragma unroll
            for (int j = 0; j < 8; ++j) { float v = q[i + j]; float sq = v * v; r[j] = r[j] + sq; }
        }
        sh[h] = ((r[0] + r[1]) + (r[2] + r[3])) + ((r[4] + r[5]) + (r[6] + r[7]));
    }
    wsq[k] = sh[0] + sh[1];
}

// ---------------------------------------------------------------- main -----
// 512 blocks x 256 threads. Block covers 128 tokens. tid = kg*32 + ti;
// thread scans codes [kg*64, kg*64+64) for tokens tbase + r*32 + ti, r<4,
// keeping per-token top-4 of m. Then merge across kg and adjudicate.
__global__ __launch_bounds__(256) void vq_main(const float* __restrict__ z_e,
                                               const float* __restrict__ cb,
                                               const float* __restrict__ wsq,
                                               float* __restrict__ out) {
    __shared__ float wch[KG * CC][DDIM];   // 64 KiB

    const int tid = threadIdx.x;
    const int kg  = tid >> 5;
    const int ti  = tid & 31;
    const int tbase = blockIdx.x * TPB;    // 128-aligned -> single n per block
    const int n   = tbase >> 10;
    const int hw0 = tbase & (HWSZ - 1);
    const float* xb = z_e + (size_t)n * (DDIM * HWSZ) + hw0 + ti;

    float bb[RTOK][4];
    int   ii[RTOK][4];
    #pragma unroll
    for (int r = 0; r < RTOK; ++r)
        #pragma unroll
        for (int c = 0; c < 4; ++c) { bb[r][c] = -FLT_MAX; ii[r][c] = KCODES; }

    const float4* cb4 = (const float4*)cb;

    for (int ch = 0; ch < NCHUNK; ++ch) {
        __syncthreads();
        {   // stage 64 rows = 4096 float4, coalesced
            float4* w4 = (float4*)&wch[0][0];
            #pragma unroll
            for (int i = 0; i < 16; ++i) {
                const int f = tid + 256 * i;          // 0..4095
                const int rowlds = f >> 6, col4 = f & 63;
                const int code = (rowlds >> 3) * CPG + ch * CC + (rowlds & 7);
                w4[f] = cb4[(size_t)code * 64 + col4];
            }
        }
        __syncthreads();

        float acc[RTOK][CC];
        #pragma unroll
        for (int r = 0; r < RTOK; ++r)
            #pragma unroll
            for (int j = 0; j < CC; ++j) acc[r][j] = 0.f;

        float xc[RTOK][4], xn[RTOK][4];
        #pragma unroll
        for (int r = 0; r < RTOK; ++r)
            #pragma unroll
            for (int q = 0; q < 4; ++q) xc[r][q] = xb[r * 32 + q * HWSZ];

        #pragma unroll 2
        for (int d4 = 0; d4 < DDIM / 4; ++d4) {
            const int dn = (d4 + 1) & 63;  // wraps on last iter (harmless reload)
            #pragma unroll
            for (int r = 0; r < RTOK; ++r)
                #pragma unroll
                for (int q = 0; q < 4; ++q) xn[r][q] = xb[r * 32 + (dn * 4 + q) * HWSZ];

            #pragma unroll
            for (int j = 0; j < CC; ++j) {
                const float4 w = *(const float4*)&wch[kg * CC + j][d4 * 4];
                #pragma unroll
                for (int r = 0; r < RTOK; ++r) {
                    float a = acc[r][j];
                    a = fmaf(xc[r][0], w.x, a);
                    a = fmaf(xc[r][1], w.y, a);
                    a = fmaf(xc[r][2], w.z, a);
                    a = fmaf(xc[r][3], w.w, a);
                    acc[r][j] = a;
                }
            }
            #pragma unroll
            for (int r = 0; r < RTOK; ++r)
                #pragma unroll
                for (int q = 0; q < 4; ++q) xc[r][q] = xn[r][q];
        }

        // finalize chunk: m = dot - 0.5*wsq, per-token top-4 (codes ascending)
        #pragma unroll
        for (int j = 0; j < CC; ++j) {
            const int code = kg * CPG + ch * CC + j;
            const float h2 = 0.5f * wsq[code];
            #pragma unroll
            for (int r = 0; r < RTOK; ++r) {
                const float m = acc[r][j] - h2;
                if (m > bb[r][3]) {
                    if (m > bb[r][1]) {
                        if (m > bb[r][0]) {
                            bb[r][3]=bb[r][2]; ii[r][3]=ii[r][2];
                            bb[r][2]=bb[r][1]; ii[r][2]=ii[r][1];
                            bb[r][1]=bb[r][0]; ii[r][1]=ii[r][0];
                            bb[r][0]=m; ii[r][0]=code;
                        } else {
                            bb[r][3]=bb[r][2]; ii[r][3]=ii[r][2];
                            bb[r][2]=bb[r][1]; ii[r][2]=ii[r][1];
                            bb[r][1]=m; ii[r][1]=code;
                        }
                    } else {
                        if (m > bb[r][2]) {
                            bb[r][3]=bb[r][2]; ii[r][3]=ii[r][2];
                            bb[r][2]=m; ii[r][2]=code;
                        } else {
                            bb[r][3]=m; ii[r][3]=code;
                        }
                    }
                }
            }
        }
    }

    // ---- publish per-group top-4 to LDS (reuse wch) ----
    __syncthreads();
    float* pmv = (float*)&wch[0][0];               // [KG*4][TPB] floats (16 KB)
    int*   piv = (int*)(pmv + KG * 4 * TPB);       // [KG*4][TPB] ints  (16 KB)
    #pragma unroll
    for (int r = 0; r < RTOK; ++r) {
        const int lidx = r * 32 + ti;
        #pragma unroll
        for (int c = 0; c < 4; ++c) {
            pmv[(kg * 4 + c) * TPB + lidx] = bb[r][c];
            piv[(kg * 4 + c) * TPB + lidx] = ii[r][c];
        }
    }
    __syncthreads();

    if (tid < TPB) {
        // global top-4 by m across the 32 published candidates
        float g[4] = {-FLT_MAX, -FLT_MAX, -FLT_MAX, -FLT_MAX};
        int   gi[4] = {KCODES, KCODES, KCODES, KCODES};
        for (int e = 0; e < KG * 4; ++e) {
            const float m = pmv[e * TPB + tid];
            const int idx = piv[e * TPB + tid];
            if (m > g[3]) {
                if (m > g[1]) {
                    if (m > g[0]) { g[3]=g[2]; gi[3]=gi[2]; g[2]=g[1]; gi[2]=gi[1];
                                    g[1]=g[0]; gi[1]=gi[0]; g[0]=m; gi[0]=idx; }
                    else          { g[3]=g[2]; gi[3]=gi[2]; g[2]=g[1]; gi[2]=gi[1];
                                    g[1]=m; gi[1]=idx; }
                } else {
                    if (m > g[2]) { g[3]=g[2]; gi[3]=gi[2]; g[2]=m; gi[2]=idx; }
                    else          { g[3]=m; gi[3]=idx; }
                }
            }
        }

        const float* xa = z_e + (size_t)n * (DDIM * HWSZ) + hw0 + tid;

        // xsq: bitwise np pairwise fp32 (2 halves x 8 accumulators)
        float xsq;
        {
#pragma clang fp contract(off)
            float sh[2];
            #pragma unroll
            for (int h = 0; h < 2; ++h) {
                float r[8];
                #pragma unroll
                for (int j = 0; j < 8; ++j) {
                    float v = xa[(h * 128 + j) * HWSZ]; r[j] = v * v;
                }
                #pragma unroll 2
                for (int i = 8; i < 128; i += 8) {
                    #pragma unroll
                    for (int j = 0; j < 8; ++j) {
                        float v = xa[(h * 128 + i + j) * HWSZ];
                        float sq = v * v;
                        r[j] = r[j] + sq;
                    }
                }
                sh[h] = ((r[0] + r[1]) + (r[2] + r[3])) + ((r[4] + r[5]) + (r[6] + r[7]));
            }
            xsq = sh[0] + sh[1];
        }

        // near-exact fp64 dots for the 4 candidates
        const float* w0 = cb + (size_t)gi[0] * DDIM;
        const float* w1 = cb + (size_t)gi[1] * DDIM;
        const float* w2 = cb + (size_t)gi[2] * DDIM;
        const float* w3 = cb + (size_t)gi[3] * DDIM;
        double A0 = 0.0, A1 = 0.0, A2 = 0.0, A3 = 0.0;
        #pragma unroll 4
        for (int d = 0; d < DDIM; ++d) {
            const double xv = (double)xa[d * HWSZ];
            A0 = fma(xv, (double)w0[d], A0);
            A1 = fma(xv, (double)w1[d], A1);
            A2 = fma(xv, (double)w2[d], A2);
            A3 = fma(xv, (double)w3[d], A3);
        }
        double A[4] = {A0, A1, A2, A3};

        // ref-identical quantized fp32 distance; tie -> lowest index
        float bestd = FLT_MAX;
        int   bestk = KCODES;
        {
#pragma clang fp contract(off)
            #pragma unroll
            for (int c = 0; c < 4; ++c) {
                const int idx = gi[c];
                const float xw = (float)A[c];
                const float t1 = xsq - 2.0f * xw;
                const float dist = t1 + wsq[idx];
                if (dist < bestd || (dist == bestd && idx < bestk)) {
                    bestd = dist; bestk = idx;
                }
            }
        }

        const int t = tbase + tid;
        out[t] = (float)bestk;

        float* zq = out + TTOK + (size_t)n * (DDIM * HWSZ) + hw0 + tid;
        const float4* rp = (const float4*)cb + (size_t)bestk * 64;
        #pragma unroll 4
        for (int d4 = 0; d4 < DDIM / 4; ++d4) {
            const float4 w = rp[d4];
            zq[(d4 * 4 + 0) * HWSZ] = w.x;
            zq[(d4 * 4 + 1) * HWSZ] = w.y;
            zq[(d4 * 4 + 2) * HWSZ] = w.z;
            zq[(d4 * 4 + 3) * HWSZ] = w.w;
        }
    }
}

// --------------------------------------------------------------- launch ----
extern "C" void kernel_launch(void* const* d_in, const int* in_sizes, int n_in,
                              void* d_out, int out_size, void* d_ws, size_t ws_size,
                              hipStream_t stream) {
    const float* z_e = (const float*)d_in[0];
    const float* cb  = (const float*)d_in[1];
    float* out = (float*)d_out;
    float* wsq = (float*)d_ws;   // 512 floats

    vq_wsq_np<<<2, 256, 0, stream>>>(cb, wsq);
    vq_main<<<NBLK, 256, 0, stream>>>(z_e, cb, wsq, out);
}

// Round 4
// 306.241 us; speedup vs baseline: 1.4817x; 1.4817x over previous
//
#include <hip/hip_runtime.h>
#include <float.h>
#include <math.h>

// VQ nearest-codebook: z_e (64,256,32,32) fp32 NCHW, codebook (512,256) fp32.
// token t = n*1024 + hw; feature d at z_e[n*262144 + d*1024 + hw].
// d_out: [0,65536) = q as float; [65536,...) = z_q fp32 NCHW.
//
// Ref model (proven R3): dists quantized by fp32 expansion with xsq~256;
// scan approximates m = x.w - 0.5|w|^2 (bf16-split MFMA, err ~2.5e-7),
// top-4 per token; if m-gap > MARGIN the argmax is final; else replicate the
// np fp32 quantized distance (xsq_np pairwise, fp64 dot -> fp32) tie->low k.

#define KCODES 512
#define DDIM   256
#define HWSZ   1024
#define TTOK   65536
#define TPB    128            // tokens per block
#define NBLK   (TTOK / TPB)   // 512
#define NCHUNK 16             // k-chunks of 16 dims
#define MARGIN 2.5e-4f

typedef short bf16x8 __attribute__((ext_vector_type(8)));   // 8 bf16 (4 VGPRs)
typedef float f32x16 __attribute__((ext_vector_type(16)));
typedef float f32x4  __attribute__((ext_vector_type(4)));

__device__ inline unsigned short bf16rne(float x) {
    union { float f; unsigned u; } a; a.f = x;
    unsigned r = a.u + (0x7fffu + ((a.u >> 16) & 1u));
    return (unsigned short)(r >> 16);
}
__device__ inline float bf16tof(unsigned short h) {
    union { unsigned u; float f; } b; b.u = ((unsigned)h) << 16; return b.f;
}

// ------------------------------------------------------------ wsq (np) -----
__global__ __launch_bounds__(256) void vq_wsq_np(const float* __restrict__ cb,
                                                 float* __restrict__ wsq) {
#pragma clang fp contract(off)
    const int k = blockIdx.x * 256 + threadIdx.x;
    if (k >= KCODES) return;
    const float* p = cb + (size_t)k * DDIM;
    float sh[2];
    #pragma unroll
    for (int h = 0; h < 2; ++h) {
        const float* q = p + h * 128;
        float r[8];
        #pragma unroll
        for (int j = 0; j < 8; ++j) { float v = q[j]; r[j] = v * v; }
        #pragma unroll
        for (int i = 8; i < 128; i += 8) {
            #pragma unroll
            for (int j = 0; j < 8; ++j) { float v = q[i + j]; float sq = v * v; r[j] = r[j] + sq; }
        }
        sh[h] = ((r[0] + r[1]) + (r[2] + r[3])) + ((r[4] + r[5]) + (r[6] + r[7]));
    }
    wsq[k] = sh[0] + sh[1];
}

// ------------------------------------------------------- w bf16 pack -------
// ws_w layout: [chunk c:16][part p:2][tile:16][lane:64][16B]  (512 KiB)
// element: code = tile*32 + (lane&31), d = c*16 + (lane>>5)*8 + j
__global__ __launch_bounds__(256) void vq_wpack(const float* __restrict__ cb,
                                                unsigned char* __restrict__ wsw) {
    const int gid = blockIdx.x * 256 + threadIdx.x;   // 16384 total
    const int k = gid >> 5, o = gid & 31;
    const int d0 = o * 8, c = o >> 1, half = o & 1;
    unsigned hi[4], lo[4];
    #pragma unroll
    for (int jj = 0; jj < 4; ++jj) {
        float v0 = cb[k * DDIM + d0 + 2 * jj];
        float v1 = cb[k * DDIM + d0 + 2 * jj + 1];
        unsigned short h0 = bf16rne(v0), h1 = bf16rne(v1);
        unsigned short l0 = bf16rne(v0 - bf16tof(h0));
        unsigned short l1 = bf16rne(v1 - bf16tof(h1));
        hi[jj] = (unsigned)h0 | ((unsigned)h1 << 16);
        lo[jj] = (unsigned)l0 | ((unsigned)l1 << 16);
    }
    const int tile = k >> 5, lane2 = (k & 31) + 32 * half;
    *(uint4*)(wsw + ((size_t)((c * 2 + 0) * 16 + tile) * 1024) + lane2 * 16) = make_uint4(hi[0], hi[1], hi[2], hi[3]);
    *(uint4*)(wsw + ((size_t)((c * 2 + 1) * 16 + tile) * 1024) + lane2 * 16) = make_uint4(lo[0], lo[1], lo[2], lo[3]);
}

// ---------------------------------------------------------------- main -----
// 512 blocks x 512 threads (8 waves). Block = 128 tokens x 512 codes.
// Wave wv handles codes [wv*64, wv*64+64) as 2 n-tiles of 32.
// x staged in LDS in A-fragment order: [p:2][mt:4][c:16][lane:64][16B] = 128 KiB.
__global__ __launch_bounds__(512, 2) void vq_main(const float* __restrict__ z_e,
                                                  const float* __restrict__ cb,
                                                  const float* __restrict__ wsq,
                                                  const unsigned char* __restrict__ wsw,
                                                  float* __restrict__ out) {
    __shared__ __align__(16) unsigned char lds[131072];
    float* scf = (float*)lds;

    const int tid = threadIdx.x;
    const int wv = tid >> 6, lane = tid & 63;
    const int tbase = blockIdx.x * TPB;
    const int n = tbase >> 10, hw0 = tbase & (HWSZ - 1);
    const float* zb = z_e + (size_t)n * (DDIM * HWSZ) + hw0;

    // ---- stage x -> LDS (bf16 hi/lo, fragment-packed, b128 writes) ----
    {
        const int tok = tid & 127, g = tid >> 7;
        const int mt = tok >> 5;
        const int lbase = (tok & 31) * 16;
        #pragma unroll
        for (int o = 0; o < 8; ++o) {
            const int d0 = g * 64 + o * 8;
            float v[8];
            #pragma unroll
            for (int j = 0; j < 8; ++j) v[j] = zb[(size_t)(d0 + j) * HWSZ + tok];
            unsigned hi[4], lo[4];
            #pragma unroll
            for (int jj = 0; jj < 4; ++jj) {
                unsigned short h0 = bf16rne(v[2 * jj]), h1 = bf16rne(v[2 * jj + 1]);
                unsigned short l0 = bf16rne(v[2 * jj] - bf16tof(h0));
                unsigned short l1 = bf16rne(v[2 * jj + 1] - bf16tof(h1));
                hi[jj] = (unsigned)h0 | ((unsigned)h1 << 16);
                lo[jj] = (unsigned)l0 | ((unsigned)l1 << 16);
            }
            const int c = d0 >> 4;
            const int off2 = lbase + 512 * ((d0 >> 3) & 1);
            *(uint4*)(lds + ((0 * 4 + mt) * 16 + c) * 1024 + off2) = make_uint4(hi[0], hi[1], hi[2], hi[3]);
            *(uint4*)(lds + ((1 * 4 + mt) * 16 + c) * 1024 + off2) = make_uint4(lo[0], lo[1], lo[2], lo[3]);
        }
    }

    f32x16 acc[4][2];
    #pragma unroll
    for (int mt = 0; mt < 4; ++mt)
        #pragma unroll
        for (int nt = 0; nt < 2; ++nt)
            #pragma unroll
            for (int r = 0; r < 16; ++r) acc[mt][nt][r] = 0.f;

    __syncthreads();

    // ---- K-loop: 16 chunks of 16 dims, 3 bf16-split passes ----
    #define LDB(c, p, nt) (*(const bf16x8*)(wsw + ((size_t)(((c) * 2 + (p)) * 16 + (wv * 2 + (nt))) * 1024) + lane * 16))
    #define LDA(p, mt, c) (*(const bf16x8*)(lds + (((p) * 4 + (mt)) * 16 + (c)) * 1024 + lane * 16))

    bf16x8 Bh[2][2], Bl[2][2];
    Bh[0][0] = LDB(0, 0, 0); Bh[0][1] = LDB(0, 0, 1);
    Bl[0][0] = LDB(0, 1, 0); Bl[0][1] = LDB(0, 1, 1);

    #pragma unroll
    for (int c = 0; c < NCHUNK; ++c) {
        const int cur = c & 1, nxt = cur ^ 1;
        if (c + 1 < NCHUNK) {
            Bh[nxt][0] = LDB(c + 1, 0, 0); Bh[nxt][1] = LDB(c + 1, 0, 1);
            Bl[nxt][0] = LDB(c + 1, 1, 0); Bl[nxt][1] = LDB(c + 1, 1, 1);
        }
        bf16x8 Ah[4], Al[4];
        #pragma unroll
        for (int mt = 0; mt < 4; ++mt) { Ah[mt] = LDA(0, mt, c); Al[mt] = LDA(1, mt, c); }
        #pragma unroll
        for (int mt = 0; mt < 4; ++mt)
            #pragma unroll
            for (int nt = 0; nt < 2; ++nt) {
                acc[mt][nt] = __builtin_amdgcn_mfma_f32_32x32x16_bf16(Ah[mt], Bh[cur][nt], acc[mt][nt], 0, 0, 0);
                acc[mt][nt] = __builtin_amdgcn_mfma_f32_32x32x16_bf16(Ah[mt], Bl[cur][nt], acc[mt][nt], 0, 0, 0);
                acc[mt][nt] = __builtin_amdgcn_mfma_f32_32x32x16_bf16(Al[mt], Bh[cur][nt], acc[mt][nt], 0, 0, 0);
            }
    }

    // ---- epilogue: scores -> LDS (2 rounds), per-token top-4 fold ----
    const float wsqv0 = wsq[wv * 64 + (lane & 31)];
    const float wsqv1 = wsq[wv * 64 + 32 + (lane & 31)];

    float fb[4] = {-FLT_MAX, -FLT_MAX, -FLT_MAX, -FLT_MAX};
    int   fi[4] = {KCODES, KCODES, KCODES, KCODES};

    #pragma unroll
    for (int r = 0; r < 2; ++r) {
        __syncthreads();
        if ((wv >> 2) == r) {
            const int clA = (wv & 3) * 64 + (lane & 31);
            const int rowb = 4 * (lane >> 5);
            #pragma unroll
            for (int mt = 0; mt < 4; ++mt)
                #pragma unroll
                for (int nt = 0; nt < 2; ++nt) {
                    const float h2 = nt ? 0.5f * wsqv1 : 0.5f * wsqv0;
                    #pragma unroll
                    for (int reg = 0; reg < 16; ++reg) {
                        const int tok = mt * 32 + (reg & 3) + 8 * (reg >> 2) + rowb;
                        scf[tok * 256 + clA + nt * 32] = acc[mt][nt][reg] - h2;
                    }
                }
        }
        __syncthreads();
        const int tk = tid >> 2, q = tid & 3;
        #pragma unroll 4
        for (int ii = 0; ii < 16; ++ii) {
            const int i4 = ii ^ (tk & 15);
            f32x4 v = *(const f32x4*)(scf + tk * 256 + q * 64 + i4 * 4);
            const int cbase = r * 256 + q * 64 + i4 * 4;
            #pragma unroll
            for (int cc = 0; cc < 4; ++cc) {
                const float m = v[cc];
                const int code = cbase + cc;
                if (m > fb[3]) {
                    if (m > fb[1]) {
                        if (m > fb[0]) {
                            fb[3]=fb[2]; fi[3]=fi[2]; fb[2]=fb[1]; fi[2]=fi[1];
                            fb[1]=fb[0]; fi[1]=fi[0]; fb[0]=m; fi[0]=code;
                        } else {
                            fb[3]=fb[2]; fi[3]=fi[2]; fb[2]=fb[1]; fi[2]=fi[1];
                            fb[1]=m; fi[1]=code;
                        }
                    } else {
                        if (m > fb[2]) { fb[3]=fb[2]; fi[3]=fi[2]; fb[2]=m; fi[2]=code; }
                        else           { fb[3]=m; fi[3]=code; }
                    }
                }
            }
        }
    }

    // ---- publish per-thread top-4, merge per token, adjudicate ----
    __syncthreads();
    float* candm = scf;                    // 2048 floats
    int*   candi = (int*)(scf + 2048);     // 2048 ints
    int*   bkArr = (int*)(scf + 4096);     // 128 ints
    #pragma unroll
    for (int c = 0; c < 4; ++c) { candm[tid * 4 + c] = fb[c]; candi[tid * 4 + c] = fi[c]; }
    __syncthreads();

    if (tid < TPB) {
        float g[4] = {-FLT_MAX, -FLT_MAX, -FLT_MAX, -FLT_MAX};
        int  gi[4] = {KCODES, KCODES, KCODES, KCODES};
        #pragma unroll
        for (int e = 0; e < 16; ++e) {
            const float m = candm[(tid * 4 + (e >> 2)) * 4 + (e & 3)];
            const int idx = candi[(tid * 4 + (e >> 2)) * 4 + (e & 3)];
            if (m > g[3]) {
                if (m > g[1]) {
                    if (m > g[0]) { g[3]=g[2]; gi[3]=gi[2]; g[2]=g[1]; gi[2]=gi[1];
                                    g[1]=g[0]; gi[1]=gi[0]; g[0]=m; gi[0]=idx; }
                    else          { g[3]=g[2]; gi[3]=gi[2]; g[2]=g[1]; gi[2]=gi[1];
                                    g[1]=m; gi[1]=idx; }
                } else {
                    if (m > g[2]) { g[3]=g[2]; gi[3]=gi[2]; g[2]=m; gi[2]=idx; }
                    else          { g[3]=m; gi[3]=idx; }
                }
            }
        }

        int bestk;
        if (g[0] - g[1] > MARGIN) {
            bestk = gi[0];     // gap >> quantization window: no tie possible
        } else {
            const float* xa = zb + tid;
            // xsq: bitwise np pairwise fp32
            float xsq;
            {
#pragma clang fp contract(off)
                float sh[2];
                #pragma unroll
                for (int h = 0; h < 2; ++h) {
                    float rr[8];
                    #pragma unroll
                    for (int j = 0; j < 8; ++j) { float v = xa[(size_t)(h * 128 + j) * HWSZ]; rr[j] = v * v; }
                    #pragma unroll 2
                    for (int i = 8; i < 128; i += 8) {
                        #pragma unroll
                        for (int j = 0; j < 8; ++j) {
                            float v = xa[(size_t)(h * 128 + i + j) * HWSZ];
                            float sq = v * v;
                            rr[j] = rr[j] + sq;
                        }
                    }
                    sh[h] = ((rr[0] + rr[1]) + (rr[2] + rr[3])) + ((rr[4] + rr[5]) + (rr[6] + rr[7]));
                }
                xsq = sh[0] + sh[1];
            }
            float bestd = FLT_MAX; bestk = KCODES;
            for (int c = 0; c < 4; ++c) {
                if (c > 0 && g[0] - g[c] > MARGIN) break;
                const int idx = gi[c];
                const float* wr = cb + (size_t)idx * DDIM;
                double A = 0.0;
                #pragma unroll 4
                for (int d = 0; d < DDIM; ++d)
                    A = fma((double)xa[(size_t)d * HWSZ], (double)wr[d], A);
                {
#pragma clang fp contract(off)
                    const float xw = (float)A;
                    const float t1 = xsq - 2.0f * xw;
                    const float dist = t1 + wsq[idx];
                    if (dist < bestd || (dist == bestd && idx < bestk)) { bestd = dist; bestk = idx; }
                }
            }
        }
        out[tbase + tid] = (float)bestk;
        bkArr[tid] = bestk;
    }
    __syncthreads();

    // ---- z_q write (coalesced over tokens) ----
    {
        const int tk = tid & 127, s = tid >> 7;
        const int bk = bkArr[tk];
        const float* wr = cb + (size_t)bk * DDIM;
        float* zq = out + TTOK + (size_t)n * (DDIM * HWSZ) + hw0 + tk;
        #pragma unroll 4
        for (int i = 0; i < 64; ++i) {
            const int d = s * 64 + i;
            zq[(size_t)d * HWSZ] = wr[d];
        }
    }
}

// --------------------------------------------------------------- launch ----
extern "C" void kernel_launch(void* const* d_in, const int* in_sizes, int n_in,
                              void* d_out, int out_size, void* d_ws, size_t ws_size,
                              hipStream_t stream) {
    const float* z_e = (const float*)d_in[0];
    const float* cb  = (const float*)d_in[1];
    float* out = (float*)d_out;
    float* wsq = (float*)d_ws;                              // 2 KiB
    unsigned char* wsw = (unsigned char*)d_ws + 2048;       // 512 KiB fragment-packed w

    vq_wsq_np<<<2, 256, 0, stream>>>(cb, wsq);
    vq_wpack<<<64, 256, 0, stream>>>(cb, wsw);
    vq_main<<<NBLK, 512, 0, stream>>>(z_e, cb, wsq, wsw, out);
}